// Round 2
// baseline (265.028 us; speedup 1.0000x reference)
//
#include <hip/hip_runtime.h>

#define BATCH 512
#define NNODE 200
#define CIN   200
#define HID   128
#define IPY   232   // padded row stride (shorts): 464B rows -> conflict-free ds_read_b128
#define KCH   7     // 7 K-chunks of 32 (cover 224 >= 200)

typedef __attribute__((ext_vector_type(4))) float  f32x4;
typedef __attribute__((ext_vector_type(4))) int    i32x4;
typedef __attribute__((ext_vector_type(8))) short  sh8;
typedef __attribute__((ext_vector_type(4))) short  sh4;
typedef __attribute__((ext_vector_type(8))) __bf16 bf16x8;

__device__ __forceinline__ short f2bf(float x) {
  union { float f; unsigned u; } v; v.f = x;
  unsigned r = v.u + 0x7FFFu + ((v.u >> 16) & 1u);   // RNE
  return (short)(r >> 16);
}
__device__ __forceinline__ f32x4 mfma16(sh8 a, sh8 b, f32x4 c) {
  return __builtin_amdgcn_mfma_f32_16x16x32_bf16(
      __builtin_bit_cast(bf16x8, a), __builtin_bit_cast(bf16x8, b), c, 0, 0, 0);
}
__device__ __forceinline__ f32x4 mfma16i(sh8 a, i32x4 b, f32x4 c) {
  return __builtin_amdgcn_mfma_f32_16x16x32_bf16(
      __builtin_bit_cast(bf16x8, a), __builtin_bit_cast(bf16x8, b), c, 0, 0, 0);
}
// expand 8 adjacency bits -> 4 dwords of packed {bf16(b_even)|bf16(b_odd)<<16}
__device__ __forceinline__ i32x4 expand8(unsigned byte_) {
  i32x4 w;
#pragma unroll
  for (int h = 0; h < 4; ++h) {
    unsigned p = byte_ >> (2 * h);
    unsigned d = ((p & 1u) ? 0x3F80u : 0u) | ((p & 2u) ? 0x3F800000u : 0u);
    w[h] = (int)d;
  }
  return w;
}

// ---------- k_prep: W1 [200][128] f32 -> W1T [128][232] bf16 (zero-padded cols) ----------
__global__ __launch_bounds__(256) void k_prep(const float* __restrict__ W1,
                                              short* __restrict__ W1T) {
  const int idx = blockIdx.x * 256 + threadIdx.x;
  const int f = idx / IPY, c = idx - f * IPY;
  W1T[idx] = (c < CIN) ? f2bf(W1[(size_t)c * HID + f]) : (short)0;
}

// ---------- k_gin: one block per batch; single adj pass, ballot-deg, x prefetch ----------
__global__ __launch_bounds__(1024) void k_gin(const float* __restrict__ x,
                                              const int* __restrict__ adj,
                                              const short* __restrict__ W1Tg,
                                              const float* __restrict__ b1,
                                              const float* __restrict__ W2,
                                              const float* __restrict__ b2,
                                              const float* __restrict__ eps1p,
                                              const float* __restrict__ eps2p,
                                              float* __restrict__ out) {
  __shared__ short    ls_w1t[HID * IPY];      // 59,392 B
  __shared__ short    ls_y  [HID * IPY];      // 59,392 B
  __shared__ unsigned ls_bits[KCH * 224];     //  6,272 B  [wd][j]: bit t = adj[wd*32+t][j]
  __shared__ int      ls_degp[4 * 224];       //  3,584 B  per-column-wave deg partials
  __shared__ float    ls_deg[224];            //    896 B
  __shared__ float    ls_part[13][2];         //    104 B

  const int b    = blockIdx.x;
  const int tid  = threadIdx.x;
  const int wave = tid >> 6, lane = tid & 63;
  const int lq   = lane >> 4, lm = lane & 15;
  const float e1 = eps1p[0], e2 = eps2p[0];
  const int* adjb = adj + (size_t)b * NNODE * NNODE;

  // ---- x prefetch: issue first, consume after barrier 1 (latency hides under ingest) ----
  f32x4 px0[KCH], px1[KCH];
  if (wave < 13) {
    const int row = min(wave * 16 + lm, NNODE - 1);
    const float* xr = x + (size_t)b * NNODE * CIN + (size_t)row * CIN;
#pragma unroll
    for (int k = 0; k < KCH; ++k) {
      const int c0 = k * 32 + lq * 8;
      f32x4 z = {0.f, 0.f, 0.f, 0.f};
      px0[k] = z; px1[k] = z;
      if (c0 < CIN) { px0[k] = *(const f32x4*)(xr + c0); px1[k] = *(const f32x4*)(xr + c0 + 4); }
    }
  }

  // ================= phase 0: single-pass adj ingest (12 waves) + staging =================
  if (wave < 12) {
    // row-group g covers rows [g*64, ...): g0 -> wd0,1 ; g1 -> wd2,3 ; g2 -> wd4,5,6
    const int g = wave >> 2, c = wave & 3;
    const int j = c * 64 + lane;
    const int jc = min(j, NNODE - 1);
    const unsigned jv = (j < NNODE) ? 1u : 0u;
    const int base = g * 64;
    unsigned wa0 = 0, wa1 = 0, wa2 = 0;
#pragma unroll
    for (int t = 0; t < 32; ++t) {           // word 0 of this group
      const int r = base + t;
      const unsigned v = (unsigned)adjb[r * NNODE + jc] & 1u;
      wa0 |= v << t;
      const unsigned long long m = __ballot(v & jv);
      if (lane == 0) ls_degp[c * 224 + r] = __popcll(m);
    }
#pragma unroll
    for (int t = 0; t < 32; ++t) {           // word 1
      const int r = base + 32 + t;
      const unsigned v = (unsigned)adjb[r * NNODE + jc] & 1u;
      wa1 |= v << t;
      const unsigned long long m = __ballot(v & jv);
      if (lane == 0) ls_degp[c * 224 + r] = __popcll(m);
    }
    if (g == 2) {
#pragma unroll
      for (int t = 0; t < 8; ++t) {          // word 2, rows 192..199 only
        const int r = 192 + t;
        const unsigned v = (unsigned)adjb[r * NNODE + jc] & 1u;
        wa2 |= v << t;
        const unsigned long long m = __ballot(v & jv);
        if (lane == 0) ls_degp[c * 224 + r] = __popcll(m);
      }
    }
    if (j < 224) {                           // bank = j%32 -> conflict-free stores
      ls_bits[(g * 2 + 0) * 224 + j] = jv ? wa0 : 0u;
      ls_bits[(g * 2 + 1) * 224 + j] = jv ? wa1 : 0u;
      if (g == 2) ls_bits[6 * 224 + j] = jv ? wa2 : 0u;
    }
  } else {
    // waves 12-15: stage W1T (58 KiB); waves 13-15 also zero ls_y pad cols
    const int wq = wave - 12;
    const int c0 = (wq == 0) ? 0 : 10 + (wq - 1) * 16;
    const int nc = (wq == 0) ? 10 : 16;
    for (int it = 0; it < nc; ++it) {
      const int ch = c0 + it;
      *(sh8*)&ls_w1t[ch * 512 + lane * 8] = *(const sh8*)(W1Tg + ch * 512 + lane * 8);
    }
    if (wave >= 13) {
      const int q = tid - 832;               // [0,192)
#pragma unroll
      for (int it = 0; it < 3; ++it) {
        const int idx = q + it * 192;        // [0,512) covers 128 rows x 4 sh8
        if (idx < 512) {
          const int f = idx >> 2, p = idx & 3;
          sh8 z = {0, 0, 0, 0, 0, 0, 0, 0};
          *(sh8*)&ls_y[f * IPY + 200 + p * 8] = z;
        }
      }
    }
  }
  __syncthreads();

  // ================= phase 1: y = x @ W1 -> LDS ; waves 13-15 finalize deg =================
  if (wave < 13) {
    const int mt = wave;
    sh8 af[KCH];
#pragma unroll
    for (int k = 0; k < KCH; ++k) {
      sh8 a;
#pragma unroll
      for (int jj = 0; jj < 4; ++jj) { a[jj] = f2bf(px0[k][jj]); a[4 + jj] = f2bf(px1[k][jj]); }
      af[k] = a;
    }
#pragma unroll 2
    for (int ft = 0; ft < 8; ++ft) {
      const int fb = ft * 16;
      const short* wr = &ls_w1t[(fb + lm) * IPY];      // conflict-free b128
      f32x4 acc = {0.f, 0.f, 0.f, 0.f};
#pragma unroll
      for (int k = 0; k < KCH; ++k)
        acc = mfma16(af[k], *(const sh8*)(wr + k * 32 + lq * 8), acc);
      sh4 st;                                          // D: n=lm->f, m=lq*4+r->i
#pragma unroll
      for (int r = 0; r < 4; ++r) st[r] = f2bf(acc[r]);
      if (mt * 16 + lq * 4 < NNODE)                    // keep pad cols exactly zero
        *(sh4*)&ls_y[(fb + lm) * IPY + mt * 16 + lq * 4] = st;
    }
  } else {
    const int q = tid - 832;                           // [0,192)
    for (int r = q; r < 224; r += 192) {
      int s = 0;
      if (r < NNODE)
        s = ls_degp[r] + ls_degp[224 + r] + ls_degp[448 + r] + ls_degp[672 + r];
      ls_deg[r] = (float)s;
    }
  }
  __syncthreads();

  // ================= phase 2: aggregate + MLP2 + pooled sum, all from LDS =================
  if (wave < 13) {
    const int jt = wave;
    const int j  = jt * 16 + lm;
    const bool jok = (j < NNODE);
    const unsigned cd0 = (unsigned)(unsigned short)f2bf(1.f + e1);   // diag, bit==0
    const unsigned cd1 = (unsigned)(unsigned short)f2bf(2.f + e1);   // diag, bit==1
    unsigned bwa[KCH];
#pragma unroll
    for (int k = 0; k < KCH; ++k) bwa[k] = ls_bits[k * 224 + j];     // j<=207 in-bounds
    i32x4 bfr[KCH];
#pragma unroll
    for (int k = 0; k < KCH; ++k) {
      const unsigned byte_ = (bwa[k] >> (lq * 8)) & 0xFFu;
      i32x4 w = expand8(byte_);
      const int d = j - (k * 32 + lq * 8);             // diag position within this byte
      if (d >= 0 && d < 8) {
        const unsigned val = ((byte_ >> d) & 1u) ? cd1 : cd0;
        const int h2 = d >> 1, sh = (d & 1) * 16;
        w[h2] = (int)(((unsigned)w[h2] & ~(0xFFFFu << sh)) | (val << sh));
      }
      bfr[k] = w;
    }
    float ga = 0.f, gb = 0.f;
#pragma unroll 2
    for (int ft = 0; ft < 8; ++ft) {
      const int fb = ft * 16;
      const short* yr = &ls_y[(fb + lm) * IPY];        // conflict-free b128
      f32x4 acc = {0.f, 0.f, 0.f, 0.f};
#pragma unroll
      for (int k = 0; k < KCH; ++k)
        acc = mfma16i(*(const sh8*)(yr + k * 32 + lq * 8), bfr[k], acc);
      const f32x4 b1v = *(const f32x4*)(b1 + fb + lq * 4);           // f = fb+lq*4+r
      const f32x4 w2a = *(const f32x4*)(W2 + (fb + lq * 4) * 2);
      const f32x4 w2b = *(const f32x4*)(W2 + (fb + lq * 4) * 2 + 4);
#pragma unroll
      for (int r = 0; r < 4; ++r) {
        const float h = fmaxf(acc[r] + b1v[r], 0.f);
        const float wc0 = (r == 0) ? w2a[0] : (r == 1) ? w2a[2] : (r == 2) ? w2b[0] : w2b[2];
        const float wc1 = (r == 0) ? w2a[1] : (r == 1) ? w2a[3] : (r == 2) ? w2b[1] : w2b[3];
        ga += h * wc0;
        gb += h * wc1;
      }
    }
    ga += __shfl_xor(ga, 16); ga += __shfl_xor(ga, 32);   // sum over lq -> full f-sum per j
    gb += __shfl_xor(gb, 16); gb += __shfl_xor(gb, 32);
    const float wj = 1.f + e2 + ls_deg[min(j, NNODE - 1)];
    float t0 = jok ? wj * ga : 0.f;
    float t1 = jok ? wj * gb : 0.f;
#pragma unroll
    for (int d = 1; d < 16; d <<= 1) { t0 += __shfl_xor(t0, d); t1 += __shfl_xor(t1, d); }
    if (lane == 0) { ls_part[jt][0] = t0; ls_part[jt][1] = t1; }
  }
  __syncthreads();

  if (tid < 2) {                                       // out fully overwritten, no atomics
    float s = 0.f;
#pragma unroll
    for (int q = 0; q < 13; ++q) s += ls_part[q][tid];
    out[b * 2 + tid] = b2[tid] + s * (1.f / NNODE);
  }
}

extern "C" void kernel_launch(void* const* d_in, const int* in_sizes, int n_in,
                              void* d_out, int out_size, void* d_ws, size_t ws_size,
                              hipStream_t stream) {
  const float* x    = (const float*)d_in[0];
  const int*   adj  = (const int*)d_in[1];
  const float* W1   = (const float*)d_in[2];
  const float* b1   = (const float*)d_in[3];
  const float* W2   = (const float*)d_in[4];
  const float* b2   = (const float*)d_in[5];
  const float* eps1 = (const float*)d_in[6];
  const float* eps2 = (const float*)d_in[7];
  float* out = (float*)d_out;

  short* W1T = (short*)d_ws;                           // 59,392 B

  k_prep<<<116, 256, 0, stream>>>(W1, W1T);
  k_gin <<<BATCH, 1024, 0, stream>>>(x, adj, W1T, b1, W2, b2, eps1, eps2, out);
}

// Round 3
// 210.976 us; speedup vs baseline: 1.2562x; 1.2562x over previous
//
#include <hip/hip_runtime.h>

#define BATCH 512
#define NNODE 200
#define CIN   200
#define HID   128
#define IPY   232   // padded row stride (shorts): 464B rows -> conflict-free ds_read_b128
#define KCH   7     // 7 K-chunks of 32 (cover 224 >= 200)

typedef __attribute__((ext_vector_type(4))) float  f32x4;
typedef __attribute__((ext_vector_type(4))) int    i32x4;
typedef __attribute__((ext_vector_type(8))) short  sh8;
typedef __attribute__((ext_vector_type(4))) short  sh4;
typedef __attribute__((ext_vector_type(8))) __bf16 bf16x8;

__device__ __forceinline__ short f2bf(float x) {
  union { float f; unsigned u; } v; v.f = x;
  unsigned r = v.u + 0x7FFFu + ((v.u >> 16) & 1u);   // RNE
  return (short)(r >> 16);
}
__device__ __forceinline__ f32x4 mfma16(sh8 a, sh8 b, f32x4 c) {
  return __builtin_amdgcn_mfma_f32_16x16x32_bf16(
      __builtin_bit_cast(bf16x8, a), __builtin_bit_cast(bf16x8, b), c, 0, 0, 0);
}
__device__ __forceinline__ f32x4 mfma16i(sh8 a, i32x4 b, f32x4 c) {
  return __builtin_amdgcn_mfma_f32_16x16x32_bf16(
      __builtin_bit_cast(bf16x8, a), __builtin_bit_cast(bf16x8, b), c, 0, 0, 0);
}
// expand 8 adjacency bits -> 4 dwords of packed {bf16(b_even)|bf16(b_odd)<<16}
__device__ __forceinline__ i32x4 expand8(unsigned byte_) {
  i32x4 w;
#pragma unroll
  for (int h = 0; h < 4; ++h) {
    unsigned p = byte_ >> (2 * h);
    unsigned d = ((p & 1u) ? 0x3F80u : 0u) | ((p & 2u) ? 0x3F800000u : 0u);
    w[h] = (int)d;
  }
  return w;
}

// ---------- k_prep: W1 [200][128] f32 -> W1T [128][232] bf16 (zero-padded cols) ----------
__global__ __launch_bounds__(256) void k_prep(const float* __restrict__ W1,
                                              short* __restrict__ W1T) {
  const int idx = blockIdx.x * 256 + threadIdx.x;
  const int f = idx / IPY, c = idx - f * IPY;
  W1T[idx] = (c < CIN) ? f2bf(W1[(size_t)c * HID + f]) : (short)0;
}

// ---------- k_gin: one block per batch; role-split phase 0, batched adj ingest ----------
__global__ __launch_bounds__(1024, 4) void k_gin(const float* __restrict__ x,
                                                 const int* __restrict__ adj,
                                                 const short* __restrict__ W1Tg,
                                                 const float* __restrict__ b1,
                                                 const float* __restrict__ W2,
                                                 const float* __restrict__ b2,
                                                 const float* __restrict__ eps1p,
                                                 const float* __restrict__ eps2p,
                                                 float* __restrict__ out) {
  __shared__ __align__(16) short    ls_w1t[HID * IPY];   // 59,392 B
  __shared__ __align__(16) short    ls_y  [HID * IPY];   // 59,392 B
  __shared__ __align__(16) unsigned ls_bits[KCH * 224];  //  6,272 B  [wd][j]
  __shared__ __align__(16) float    ls_deg[224];         //    896 B
  __shared__               float    ls_part[13][2];      //    104 B

  const int b    = blockIdx.x;
  const int tid  = threadIdx.x;
  const int wave = tid >> 6, lane = tid & 63;
  const int lq   = lane >> 4, lm = lane & 15;
  const int* adjb = adj + (size_t)b * NNODE * NNODE;

  sh8 af[KCH];                                           // x fragments, live across barrier

  if (wave >= 13) {
    // ============ adj ingest, 3 waves: rows 0-63 / 64-127 / 128-199 ============
    // Batched: 32 loads in flight, THEN ballots/packing -> ~8 latency exposures/wave.
    const int iw  = wave - 13;
    const int wd0 = iw * 2, wd1 = (iw == 2) ? 7 : iw * 2 + 2;
    const int jc3 = min(192 + lane, NNODE - 1);
    for (int wd = wd0; wd < wd1; ++wd) {
      const int tmax = (wd == 6) ? 8 : 32;
      unsigned w0 = 0, w1 = 0, w2 = 0, w3 = 0;
      for (int t8 = 0; t8 < tmax; t8 += 8) {
        int v0[8], v1[8], v2[8], v3[8];
#pragma unroll
        for (int rr = 0; rr < 8; ++rr) {                 // 32 independent loads
          const int* rp = adjb + (wd * 32 + t8 + rr) * NNODE;
          v0[rr] = rp[lane]; v1[rr] = rp[64 + lane];
          v2[rr] = rp[128 + lane]; v3[rr] = rp[jc3];
        }
#pragma unroll
        for (int rr = 0; rr < 8; ++rr) {                 // pack + ballot-deg
          const int t = t8 + rr;
          const unsigned b0 = (unsigned)v0[rr] & 1u;
          const unsigned b1_ = (unsigned)v1[rr] & 1u;
          const unsigned b2_ = (unsigned)v2[rr] & 1u;
          const unsigned b3_ = (lane < 8) ? ((unsigned)v3[rr] & 1u) : 0u;
          w0 |= b0 << t; w1 |= b1_ << t; w2 |= b2_ << t; w3 |= b3_ << t;
          const int dg = __popcll(__ballot(b0 != 0u)) + __popcll(__ballot(b1_ != 0u))
                       + __popcll(__ballot(b2_ != 0u)) + __popcll(__ballot(b3_ != 0u));
          if (lane == 0) ls_deg[wd * 32 + t] = (float)dg;
        }
      }
      unsigned* bp = &ls_bits[wd * 224];                 // bank = j%32: conflict-free
      bp[lane] = w0; bp[64 + lane] = w1; bp[128 + lane] = w2;
      if (lane < 32) bp[192 + lane] = w3;                // zeroes pad cols 200-223 too
    }
  } else {
    // ============ stage W1T + x gather + y-pad zero + bf16 convert ============
    sh8 sc[5];
    int chs[5];
#pragma unroll
    for (int it = 0; it < 5; ++it) {                     // 58 chunks over 13 waves
      chs[it] = wave + it * 13;
      if (chs[it] < 58) sc[it] = ((const sh8*)W1Tg)[chs[it] * 64 + lane];
    }
    f32x4 px0[KCH], px1[KCH];                            // issued before stage writes
    const int row = min(wave * 16 + lm, NNODE - 1);
    const float* xr = x + (size_t)b * NNODE * CIN + (size_t)row * CIN;
#pragma unroll
    for (int k = 0; k < KCH; ++k) {
      const int c0 = k * 32 + lq * 8;
      f32x4 z = {0.f, 0.f, 0.f, 0.f};
      px0[k] = z; px1[k] = z;
      if (c0 < CIN) { px0[k] = *(const f32x4*)(xr + c0); px1[k] = *(const f32x4*)(xr + c0 + 4); }
    }
#pragma unroll
    for (int it = 0; it < 5; ++it)                       // waits only on sc loads
      if (chs[it] < 58) ((sh8*)ls_w1t)[chs[it] * 64 + lane] = sc[it];
    if (tid < 384) {                                     // zero ls_y cols 200-223
      const int f = tid / 3, p = tid - f * 3;
      sh8 z = {0, 0, 0, 0, 0, 0, 0, 0};
      *(sh8*)&ls_y[f * IPY + 200 + p * 8] = z;
    }
#pragma unroll
    for (int k = 0; k < KCH; ++k) {                      // px dies here; af = 28 VGPRs
      sh8 a;
#pragma unroll
      for (int jj = 0; jj < 4; ++jj) { a[jj] = f2bf(px0[k][jj]); a[4 + jj] = f2bf(px1[k][jj]); }
      af[k] = a;
    }
  }
  __syncthreads();

  // ================= phase 1: y = x @ W1 -> LDS (waves 0-12) =================
  if (wave < 13) {
    const int mt = wave;
#pragma unroll 2
    for (int ft = 0; ft < 8; ++ft) {
      const int fb = ft * 16;
      const short* wr = &ls_w1t[(fb + lm) * IPY];        // conflict-free b128
      f32x4 acc = {0.f, 0.f, 0.f, 0.f};
#pragma unroll
      for (int k = 0; k < KCH; ++k)
        acc = mfma16(af[k], *(const sh8*)(wr + k * 32 + lq * 8), acc);
      sh4 st;                                            // D: n=lm->f, m=lq*4+r->i
#pragma unroll
      for (int r = 0; r < 4; ++r) st[r] = f2bf(acc[r]);
      if (mt * 16 + lq * 4 < NNODE)                      // keep pad cols exactly zero
        *(sh4*)&ls_y[(fb + lm) * IPY + mt * 16 + lq * 4] = st;
    }
  }
  __syncthreads();

  // ================= phase 2: aggregate + MLP2 + pooled sum (waves 0-12) =================
  if (wave < 13) {
    const float e1 = eps1p[0], e2 = eps2p[0];
    const int jt = wave;
    const int j  = jt * 16 + lm;
    const bool jok = (j < NNODE);
    const unsigned cd0 = (unsigned)(unsigned short)f2bf(1.f + e1);   // diag, bit==0
    const unsigned cd1 = (unsigned)(unsigned short)f2bf(2.f + e1);   // diag, bit==1
    unsigned bwa[KCH];
#pragma unroll
    for (int k = 0; k < KCH; ++k) bwa[k] = ls_bits[k * 224 + j];     // j<=207 in-bounds
    i32x4 bfr[KCH];
#pragma unroll
    for (int k = 0; k < KCH; ++k) {
      const unsigned byte_ = (bwa[k] >> (lq * 8)) & 0xFFu;
      i32x4 w = expand8(byte_);
      const int d = j - (k * 32 + lq * 8);               // diag position within this byte
      if (d >= 0 && d < 8) {
        const unsigned val = ((byte_ >> d) & 1u) ? cd1 : cd0;
        const int h2 = d >> 1, sh = (d & 1) * 16;
        w[h2] = (int)(((unsigned)w[h2] & ~(0xFFFFu << sh)) | (val << sh));
      }
      bfr[k] = w;
    }
    float ga = 0.f, gb = 0.f;
#pragma unroll 2
    for (int ft = 0; ft < 8; ++ft) {
      const int fb = ft * 16;
      const short* yr = &ls_y[(fb + lm) * IPY];          // conflict-free b128
      f32x4 acc = {0.f, 0.f, 0.f, 0.f};
#pragma unroll
      for (int k = 0; k < KCH; ++k)
        acc = mfma16i(*(const sh8*)(yr + k * 32 + lq * 8), bfr[k], acc);
      const f32x4 b1v = *(const f32x4*)(b1 + fb + lq * 4);           // f = fb+lq*4+r
      const f32x4 w2a = *(const f32x4*)(W2 + (fb + lq * 4) * 2);
      const f32x4 w2b = *(const f32x4*)(W2 + (fb + lq * 4) * 2 + 4);
#pragma unroll
      for (int r = 0; r < 4; ++r) {
        const float h = fmaxf(acc[r] + b1v[r], 0.f);
        const float wc0 = (r == 0) ? w2a[0] : (r == 1) ? w2a[2] : (r == 2) ? w2b[0] : w2b[2];
        const float wc1 = (r == 0) ? w2a[1] : (r == 1) ? w2a[3] : (r == 2) ? w2b[1] : w2b[3];
        ga += h * wc0;
        gb += h * wc1;
      }
    }
    ga += __shfl_xor(ga, 16); ga += __shfl_xor(ga, 32);  // sum over lq -> full f-sum per j
    gb += __shfl_xor(gb, 16); gb += __shfl_xor(gb, 32);
    const float wj = 1.f + e2 + ls_deg[min(j, NNODE - 1)];
    float t0 = jok ? wj * ga : 0.f;
    float t1 = jok ? wj * gb : 0.f;
#pragma unroll
    for (int d = 1; d < 16; d <<= 1) { t0 += __shfl_xor(t0, d); t1 += __shfl_xor(t1, d); }
    if (lane == 0) { ls_part[jt][0] = t0; ls_part[jt][1] = t1; }
  }
  __syncthreads();

  if (tid < 2) {                                         // out fully overwritten, no atomics
    float s = 0.f;
#pragma unroll
    for (int q = 0; q < 13; ++q) s += ls_part[q][tid];
    out[b * 2 + tid] = b2[tid] + s * (1.f / NNODE);
  }
}

extern "C" void kernel_launch(void* const* d_in, const int* in_sizes, int n_in,
                              void* d_out, int out_size, void* d_ws, size_t ws_size,
                              hipStream_t stream) {
  const float* x    = (const float*)d_in[0];
  const int*   adj  = (const int*)d_in[1];
  const float* W1   = (const float*)d_in[2];
  const float* b1   = (const float*)d_in[3];
  const float* W2   = (const float*)d_in[4];
  const float* b2   = (const float*)d_in[5];
  const float* eps1 = (const float*)d_in[6];
  const float* eps2 = (const float*)d_in[7];
  float* out = (float*)d_out;

  short* W1T = (short*)d_ws;                             // 59,392 B

  k_prep<<<116, 256, 0, stream>>>(W1, W1T);
  k_gin <<<BATCH, 1024, 0, stream>>>(x, adj, W1T, b1, W2, b2, eps1, eps2, out);
}